// Round 9
// baseline (247.051 us; speedup 1.0000x reference)
//
#include <hip/hip_runtime.h>
#include <math.h>

// Problem constants: D_MODEL=4, D_INNER=8, D_STATE=16, D_CONV=4, DT_RANK=1
// x: (B=4, N=6, H=128, W=128) f32. L = 98304.
#define HWSZ  16384
#define LTOT  98304
#define NB    4
#define TCH   96           // chunk length
#define NCH   1024         // LTOT / TCH
#define SD    100          // k_scan t-stride: %4==0 (b128 align), d-offset 4 banks (2-way max = free)
#define NBL   (NB * LTOT)

// fast transcendentals: v_exp/v_log/v_rcp based; rel err ~1e-7, budget 2.7e-4
__device__ __forceinline__ float siluf(float x){
  return x * __builtin_amdgcn_rcpf(1.f + __expf(-x));
}
__device__ __forceinline__ float softplusf(float x){
  return fmaxf(x, 0.f) + __logf(1.f + __expf(-fabsf(x)));
}

// 16-lane (row-aligned) sum via DPP butterflies — pure VALU, no DS ops.
__device__ __forceinline__ float red16(float x){
  int v;
  v = __float_as_int(x);
  x += __int_as_float(__builtin_amdgcn_update_dpp(0, v, 0xB1, 0xF, 0xF, true));   // quad_perm xor1
  v = __float_as_int(x);
  x += __int_as_float(__builtin_amdgcn_update_dpp(0, v, 0x4E, 0xF, 0xF, true));   // quad_perm xor2
  v = __float_as_int(x);
  x += __int_as_float(__builtin_amdgcn_update_dpp(0, v, 0x141, 0xF, 0xF, true));  // row_half_mirror
  v = __float_as_int(x);
  x += __int_as_float(__builtin_amdgcn_update_dpp(0, v, 0x140, 0xF, 0xF, true));  // row_mirror
  return x;
}

// floor(sqrt(v)) exact for 0 <= v <= 2^24 via rn + one-step fixup
__device__ __forceinline__ int isqrt_floor(int v){
  int r = __float2int_rn(sqrtf((float)v));
  if (r * r > v) --r;
  else if ((r + 1) * (r + 1) <= v) ++r;
  return r;
}

// ---------------- prep: spinv (analytic stable rank) + input scatter + out zero -------------
// spinv[j] = stable rank of spatial j in d2-argsort; xs0/xs1 = scanA/scanB-ordered sequences.
__global__ __launch_bounds__(128) void k_prep(const float* __restrict__ X,
                                              int* __restrict__ spinv,
                                              float* __restrict__ xs0,
                                              float* __restrict__ xs1,
                                              float* __restrict__ out){
  const int j = blockIdx.x * 128 + threadIdx.x;   // 0..16383
  // zero out (atomic accumulation target; harness poisons it to 0xAA)
  {
    float4* o4 = (float4*)out;
    const float4 z4 = make_float4(0.f, 0.f, 0.f, 0.f);
    for (int k = j; k < NBL / 4; k += HWSZ) o4[k] = z4;
  }
  const int y = j >> 7, x = j & 127;
  const int dy = y - 64, dx = x - 64;
  const int v = dy*dy + dx*dx;
  // strictly-smaller-d2 count: clipped circle, rows dy' in [-64,63], cols dx' in [-64,63]
  int cnt = 0;
  for (int yy = 0; yy < 128; ++yy){
    int dyy = yy - 64;
    int w = v - dyy*dyy;                          // need dx'^2 < w
    if (w > 0){
      int m = isqrt_floor(w - 1);                 // largest |dx'| with dx'^2 < w
      int lo = m < 64 ? m : 64;
      int hi = m < 63 ? m : 63;
      cnt += lo + hi + 1;
    }
  }
  // same-bin (d2 == v), smaller flat index: rows above, plus same-row mirror
  {
    const int r = isqrt_floor(v);
    int yp0 = 64 - r; if (yp0 < 0) yp0 = 0;
    int yp1 = 64 + r + 1; if (yp1 > y) yp1 = y;
    for (int yp = yp0; yp < yp1; ++yp){
      int dyp = yp - 64;
      int tt = v - dyp*dyp;                       // >= 0 by construction
      int rr = isqrt_floor(tt);
      if (rr * rr == tt){
        cnt += (rr <= 64) ? 1 : 0;                // x = 64 - rr
        cnt += (rr >= 1 && rr <= 63) ? 1 : 0;     // x = 64 + rr, distinct
      }
    }
    if (x > 64) cnt += 1;                         // same-row mirror 128-x precedes
  }
  spinv[j] = cnt;
  // scatter input into scan orders: xs0[b][m*HW+cnt] = X[b][m*HW+j];
  // xs1[b][cnt*6 + n] = X[b][m*HW+j], n = (cnt even)? m : 5-m
  #pragma unroll
  for (int b = 0; b < NB; ++b){
    const float* Xb = X + (size_t)b * LTOT;
    float* p0 = xs0 + (size_t)b * LTOT;
    float* p1 = xs1 + (size_t)b * LTOT;
    #pragma unroll
    for (int m = 0; m < 6; ++m){
      const float xv = Xb[m * HWSZ + j];
      p0[m * HWSZ + cnt] = xv;
      const int n1 = (cnt & 1) ? (5 - m) : m;
      p1[cnt * 6 + n1] = xv;
    }
  }
}

// ---------------- pass 1: per-chunk pipeline + from-zero scan; caches xm/zs/sigma -----------
__global__ __launch_bounds__(128, 4)
void k_scan(const float* __restrict__ xs0, const float* __restrict__ xs1,
            const float* __restrict__ dww, const float* __restrict__ dwb,
            const float* __restrict__ ipw,
            const float* __restrict__ c1w, const float* __restrict__ c1b,
            const float* __restrict__ xpw,
            const float* __restrict__ dtpw, const float* __restrict__ dtpb,
            const float* __restrict__ Alog,
            float* __restrict__ chA, float* __restrict__ chB,
            float* __restrict__ y0g,
            float* __restrict__ xmg, float* __restrict__ zsg,
            float* __restrict__ sgg)
{
  const int c = blockIdx.x, b = blockIdx.y;
  const int c0 = c * TCH;
  const int tid = threadIdx.x;
  const size_t cb = (size_t)b * NCH + c;

  __shared__ __align__(16) float s_pre[(TCH + 3) * 9];
  __shared__ __align__(16) float s_dt[8 * SD];
  __shared__ __align__(16) float s_dxm[8 * SD];     // dt * xm (s-independent product)
  __shared__ __align__(16) float s_Bv[16 * SD];
  __shared__ __align__(16) float s_Cv[16 * SD];

  // ---- step A: contiguous loads from pre-permuted xs -> dwconv+silu -> in_proj; cache zs
  if (tid < TCH + 3){
    const int m = tid;
    const int i = c0 - 3 + m;
    if (i < 0){
      #pragma unroll
      for (int d = 0; d < 8; ++d) s_pre[m*9 + d] = 0.f;
    } else {
      const float* p0 = xs0 + (size_t)b * LTOT;
      const float* p1 = xs1 + (size_t)b * LTOT;
      const int iL = LTOT - 1 - i;
      const bool okm = (i > 0), okp = (i < LTOT - 1);
      float xv[12];
      xv[0]  = okm ? p0[i - 1]  : 0.f;
      xv[1]  =       p0[i];
      xv[2]  = okp ? p0[i + 1]  : 0.f;
      xv[3]  = okm ? p1[i - 1]  : 0.f;
      xv[4]  =       p1[i];
      xv[5]  = okp ? p1[i + 1]  : 0.f;
      xv[6]  = okm ? p0[iL + 1] : 0.f;
      xv[7]  =       p0[iL];
      xv[8]  = okp ? p0[iL - 1] : 0.f;
      xv[9]  = okm ? p1[iL + 1] : 0.f;
      xv[10] =       p1[iL];
      xv[11] = okp ? p1[iL - 1] : 0.f;
      float u[4];
      #pragma unroll
      for (int k = 0; k < 4; ++k){
        float acc = dwb[k];
        acc = fmaf(dww[k*3+0], xv[k*3+0], acc);
        acc = fmaf(dww[k*3+1], xv[k*3+1], acc);
        acc = fmaf(dww[k*3+2], xv[k*3+2], acc);
        u[k] = siluf(acc);
      }
      #pragma unroll
      for (int d = 0; d < 8; ++d){
        float acc =      ipw[d*4+0] * u[0];
        acc = fmaf(ipw[d*4+1], u[1], acc);
        acc = fmaf(ipw[d*4+2], u[2], acc);
        acc = fmaf(ipw[d*4+3], u[3], acc);
        s_pre[m*9 + d] = acc;
      }
      if (m >= 3){                                  // z gate -> global cache
        const int t0 = m - 3;
        float zs8[8];
        #pragma unroll
        for (int d = 0; d < 8; ++d){
          float acc =      ipw[(8+d)*4+0] * u[0];
          acc = fmaf(ipw[(8+d)*4+1], u[1], acc);
          acc = fmaf(ipw[(8+d)*4+2], u[2], acc);
          acc = fmaf(ipw[(8+d)*4+3], u[3], acc);
          zs8[d] = siluf(acc);
        }
        float* pz = zsg + (cb*96 + t0)*8;
        *reinterpret_cast<float4*>(pz)     = make_float4(zs8[0], zs8[1], zs8[2], zs8[3]);
        *reinterpret_cast<float4*>(pz + 4) = make_float4(zs8[4], zs8[5], zs8[6], zs8[7]);
      }
    }
  }
  __syncthreads();

  // ---- step B: conv4+silu -> xm (cached) ; x_proj -> dt, B, C (C stays in LDS)
  if (tid < TCH){
    const int t = tid;
    float xm[8];
    #pragma unroll
    for (int d = 0; d < 8; ++d){
      float acc = c1b[d];
      #pragma unroll
      for (int tau = 0; tau < 4; ++tau)
        acc = fmaf(c1w[d*4+tau], s_pre[(t+tau)*9 + d], acc);
      xm[d] = siluf(acc);
    }
    {
      float* px = xmg + (cb*96 + t)*8;
      *reinterpret_cast<float4*>(px)     = make_float4(xm[0], xm[1], xm[2], xm[3]);
      *reinterpret_cast<float4*>(px + 4) = make_float4(xm[4], xm[5], xm[6], xm[7]);
    }
    float dtr = xpw[0] * xm[0];
    #pragma unroll
    for (int d = 1; d < 8; ++d) dtr = fmaf(xpw[d], xm[d], dtr);
    #pragma unroll
    for (int s = 0; s < 16; ++s){
      float acc = xpw[(1+s)*8] * xm[0];
      #pragma unroll
      for (int d = 1; d < 8; ++d) acc = fmaf(xpw[(1+s)*8+d], xm[d], acc);
      s_Bv[s*SD + t] = acc;
      float acc2 = xpw[(17+s)*8] * xm[0];
      #pragma unroll
      for (int d = 1; d < 8; ++d) acc2 = fmaf(xpw[(17+s)*8+d], xm[d], acc2);
      s_Cv[s*SD + t] = acc2;
    }
    #pragma unroll
    for (int d = 0; d < 8; ++d){
      float dtv = softplusf(fmaf(dtpw[d], dtr, dtpb[d]));
      s_dt[d*SD + t]  = dtv;
      s_dxm[d*SD + t] = dtv * xm[d];
    }
  }
  __syncthreads();

  // ---- step C: from-zero scan; emit y0 + sigma (s==0 lanes), chunk summary
  {
    const int d = tid >> 4, s = tid & 15;
    const float Ads = -__expf(Alog[tid]);   // tid == d*16+s
    float h = 0.f, sdt = 0.f;
    const float* pdt = s_dt + d*SD;
    const float* pdx = s_dxm + d*SD;
    const float* pB  = s_Bv + s*SD;
    const float* pC  = s_Cv + s*SD;
    float* yb = y0g + cb * 768 + d * 96;
    float* sb = sgg + (cb*8 + d) * 96;
    for (int t0 = 0; t0 < TCH; t0 += 4){
      const float4 dt4 = *reinterpret_cast<const float4*>(pdt + t0);
      const float4 dx4 = *reinterpret_cast<const float4*>(pdx + t0);
      const float4 B4  = *reinterpret_cast<const float4*>(pB + t0);
      const float4 C4  = *reinterpret_cast<const float4*>(pC + t0);
      // running inclusive cumsum (serial order preserved)
      float r0 = sdt + dt4.x, r1 = r0 + dt4.y, r2 = r1 + dt4.z, r3 = r2 + dt4.w;
      sdt = r3;
      float y0, y1, y2, y3;
      { float dA = __expf(dt4.x*Ads); h = fmaf(dA, h, dx4.x*B4.x); y0 = h*C4.x; }
      { float dA = __expf(dt4.y*Ads); h = fmaf(dA, h, dx4.y*B4.y); y1 = h*C4.y; }
      { float dA = __expf(dt4.z*Ads); h = fmaf(dA, h, dx4.z*B4.z); y2 = h*C4.z; }
      { float dA = __expf(dt4.w*Ads); h = fmaf(dA, h, dx4.w*B4.w); y3 = h*C4.w; }
      y0 = red16(y0); y1 = red16(y1); y2 = red16(y2); y3 = red16(y3);
      if (s == 0){
        *reinterpret_cast<float4*>(yb + t0) = make_float4(y0, y1, y2, y3);
        *reinterpret_cast<float4*>(sb + t0) = make_float4(r0, r1, r2, r3);
      }
    }
    const size_t base = cb * 128 + tid;
    chA[base] = __expf(Ads * sdt);          // product of dA over the chunk
    chB[base] = h;
  }
}

// ---------------- combine: wave-parallel scan over chunks -> full h_in per chunk ------------
__global__ __launch_bounds__(128) void k_comb(const float* __restrict__ chA,
                                              const float* __restrict__ chB,
                                              float* __restrict__ hin){
  const int wave = (blockIdx.x << 1) | (threadIdx.x >> 6);  // 0..511 chain id
  const int lane = threadIdx.x & 63;
  const int b   = wave >> 7;
  const int idx = wave & 127;
  const size_t basebi = (size_t)b * NCH * 128 + idx;
  float carry = 0.f;
  float a = chA[basebi + (size_t)lane * 128];
  float h = chB[basebi + (size_t)lane * 128];
  for (int seg = 0; seg < NCH / 64; ++seg){
    float aN = 1.f, hN = 0.f;
    if (seg + 1 < NCH / 64){
      const size_t off = basebi + (size_t)((seg + 1) * 64 + lane) * 128;
      aN = chA[off]; hN = chB[off];
    }
    #pragma unroll
    for (int o = 1; o < 64; o <<= 1){
      float aj = __shfl_up(a, o, 64);
      float hj = __shfl_up(h, o, 64);
      if (lane >= o){ h = fmaf(a, hj, h); a *= aj; }
    }
    float ae = __shfl_up(a, 1, 64);
    float he = __shfl_up(h, 1, 64);
    if (lane == 0){ ae = 1.f; he = 0.f; }
    hin[basebi + (size_t)(seg * 64 + lane) * 128] = fmaf(ae, carry, he);
    float aL = __shfl(a, 63, 64);
    float hL = __shfl(h, 63, 64);
    carry = fmaf(aL, carry, hL);
    a = aN; h = hN;
  }
}

// ---------------- pass 2: correction + epilogue + inverse-perm scatter to out ---------------
__global__ __launch_bounds__(128)
void k_corr(const float* __restrict__ xmg, const float* __restrict__ zsg,
            const float* __restrict__ sgg, const float* __restrict__ y0g,
            const float* __restrict__ hin,
            const float* __restrict__ xpw,
            const float* __restrict__ Alog, const float* __restrict__ Dp,
            const float* __restrict__ opw,
            const float* __restrict__ lng, const float* __restrict__ lnb,
            const int* __restrict__ spinv,
            float* __restrict__ out)
{
  const int c = blockIdx.x, b = blockIdx.y;
  const int c0 = c * TCH;
  const int tid = threadIdx.x;
  const size_t cb = (size_t)b * NCH + c;

  __shared__ float s_hA[256];                   // [0:128) hin, [128:256) Ads
  __shared__ __align__(16) float s_Ct[96 * 20]; // C transposed [t][s], stride 20
  __shared__ float s_yf[8 * 96];

  // stage 0: constants
  s_hA[tid]       = hin[cb * 128 + tid];
  s_hA[128 + tid] = -__expf(Alog[tid]);

  // stage 1: rebuild C from cached xm (one row of x_proj per s)
  if (tid < TCH){
    const float* px = xmg + (cb*96 + tid)*8;
    const float4 xa = *reinterpret_cast<const float4*>(px);
    const float4 xb = *reinterpret_cast<const float4*>(px + 4);
    const float xm8[8] = {xa.x, xa.y, xa.z, xa.w, xb.x, xb.y, xb.z, xb.w};
    float* pct = s_Ct + tid*20;
    #pragma unroll
    for (int s = 0; s < 16; ++s){
      float acc = xpw[(17+s)*8] * xm8[0];
      #pragma unroll
      for (int d = 1; d < 8; ++d) acc = fmaf(xpw[(17+s)*8+d], xm8[d], acc);
      pct[s] = acc;
    }
  }
  __syncthreads();

  // stage 2: correction, lanes = (d, tsub), in-register s-accumulation
  {
    const int d = tid >> 4, tsub = tid & 15;
    float w[16], A16[16];
    #pragma unroll
    for (int s = 0; s < 16; ++s){
      w[s]   = s_hA[d*16 + s];
      A16[s] = s_hA[128 + d*16 + s];
    }
    const float* psg = sgg + (cb*8 + d) * 96;
    const float* py0 = y0g + cb * 768 + d * 96;
    #pragma unroll
    for (int t = tsub; t < TCH; t += 16){
      const float sg = psg[t];
      float acc = py0[t];
      const float* pc = s_Ct + t*20;
      #pragma unroll
      for (int s4 = 0; s4 < 16; s4 += 4){
        const float4 C4 = *reinterpret_cast<const float4*>(pc + s4);
        acc = fmaf(C4.x, __expf(A16[s4+0]*sg) * w[s4+0], acc);
        acc = fmaf(C4.y, __expf(A16[s4+1]*sg) * w[s4+1], acc);
        acc = fmaf(C4.z, __expf(A16[s4+2]*sg) * w[s4+2], acc);
        acc = fmaf(C4.w, __expf(A16[s4+3]*sg) * w[s4+3], acc);
      }
      s_yf[d*96 + t] = acc;
    }
  }
  __syncthreads();

  // stage 3: epilogue (skip+gate+out_proj+LN) + scatter via inverse perms
  if (tid < TCH){
    const int t = tid;
    const int i = c0 + t;
    const float* px = xmg + (cb*96 + t)*8;
    const float* pz = zsg + (cb*96 + t)*8;
    const float4 xa = *reinterpret_cast<const float4*>(px);
    const float4 xb = *reinterpret_cast<const float4*>(px + 4);
    const float4 za = *reinterpret_cast<const float4*>(pz);
    const float4 zb = *reinterpret_cast<const float4*>(pz + 4);
    const float xm8[8] = {xa.x, xa.y, xa.z, xa.w, xb.x, xb.y, xb.z, xb.w};
    const float zs8[8] = {za.x, za.y, za.z, za.w, zb.x, zb.y, zb.z, zb.w};
    float y[8];
    #pragma unroll
    for (int d = 0; d < 8; ++d)
      y[d] = (s_yf[d*96 + t] + xm8[d] * Dp[d]) * zs8[d];
    float o[4];
    #pragma unroll
    for (int e = 0; e < 4; ++e){
      float acc = opw[e*8] * y[0];
      #pragma unroll
      for (int d = 1; d < 8; ++d) acc = fmaf(opw[e*8+d], y[d], acc);
      o[e] = acc;
    }
    const float mu = 0.25f * (o[0] + o[1] + o[2] + o[3]);
    const float v0 = o[0] - mu, v1 = o[1] - mu, v2 = o[2] - mu, v3 = o[3] - mu;
    const float inv = rsqrtf(0.25f * (v0*v0 + v1*v1 + v2*v2 + v3*v3) + 1e-5f);
    const float w0 = fmaf(v0 * inv, lng[0], lnb[0]);
    const float w1 = fmaf(v1 * inv, lng[1], lnb[1]);
    const float w2 = fmaf(v2 * inv, lng[2], lnb[2]);
    const float w3 = fmaf(v3 * inv, lng[3], lnb[3]);
    // inverse perms: e0: l0 = n*HW + r; e1: l1 = r*6 + ((r odd)? 5-n : n); e2/e3 reversed
    const int n = i >> 14, j = i & (HWSZ - 1);
    const int r = spinv[j];
    const int l0 = (n << 14) + r;
    const int n1 = (r & 1) ? (5 - n) : n;
    const int l1 = r * 6 + n1;
    float* ob = out + (size_t)b * LTOT;
    atomicAdd(ob + l0,            0.25f * w0);
    atomicAdd(ob + l1,            0.25f * w1);
    atomicAdd(ob + (LTOT-1 - l0), 0.25f * w2);
    atomicAdd(ob + (LTOT-1 - l1), 0.25f * w3);
  }
}

extern "C" void kernel_launch(void* const* d_in, const int* in_sizes, int n_in,
                              void* d_out, int out_size, void* d_ws, size_t ws_size,
                              hipStream_t stream) {
  const float* X    = (const float*)d_in[0];   // (4,6,128,128)
  const float* dww  = (const float*)d_in[1];   // (4,1,3)
  const float* dwb  = (const float*)d_in[2];   // (4)
  const float* ipw  = (const float*)d_in[3];   // (16,4)
  const float* c1w  = (const float*)d_in[4];   // (8,1,4)
  const float* c1b  = (const float*)d_in[5];   // (8)
  const float* xpw  = (const float*)d_in[6];   // (33,8)
  const float* dtpw = (const float*)d_in[7];   // (8,1)
  const float* dtpb = (const float*)d_in[8];   // (8)
  const float* Alog = (const float*)d_in[9];   // (8,16)
  const float* Dp   = (const float*)d_in[10];  // (8)
  const float* opw  = (const float*)d_in[11];  // (4,8)
  const float* lng  = (const float*)d_in[12];  // (4)
  const float* lnb  = (const float*)d_in[13];  // (4)
  float* out = (float*)d_out;

  // workspace layout (all rewritten every call), ~63 MB:
  //   spinv 16384 int | xs0/xs1 2 x 393216 f32 | chA/chB/hin 3 x 524288 f32
  //   y0g 3145728 | xmg/zsg/sgg 3 x 3145728   (f32)
  int* wsI     = (int*)d_ws;
  int* spinv   = wsI;
  float* xs0   = (float*)(wsI + 16384);
  float* xs1   = xs0 + NBL;
  float* chA   = xs1 + NBL;
  float* chB   = chA + 524288;
  float* hin   = chB + 524288;
  float* y0g   = hin + 524288;
  float* xmg   = y0g + 3145728;
  float* zsg   = xmg + 3145728;
  float* sgg   = zsg + 3145728;

  k_prep<<<128, 128, 0, stream>>>(X, spinv, xs0, xs1, out);
  k_scan<<<dim3(NCH, NB), 128, 0, stream>>>(xs0, xs1, dww, dwb, ipw, c1w, c1b, xpw,
      dtpw, dtpb, Alog, chA, chB, y0g, xmg, zsg, sgg);
  k_comb<<<256, 128, 0, stream>>>(chA, chB, hin);
  k_corr<<<dim3(NCH, NB), 128, 0, stream>>>(xmg, zsg, sgg, y0g, hin,
      xpw, Alog, Dp, opw, lng, lnb, spinv, out);
}

// Round 10
// 194.287 us; speedup vs baseline: 1.2716x; 1.2716x over previous
//
#include <hip/hip_runtime.h>
#include <math.h>

// Problem constants: D_MODEL=4, D_INNER=8, D_STATE=16, D_CONV=4, DT_RANK=1
// x: (B=4, N=6, H=128, W=128) f32. L = 98304.
#define HWSZ  16384
#define LTOT  98304
#define NB    4
#define TCH   96           // chunk length
#define NCH   1024         // LTOT / TCH
#define SD    100          // k_scan t-stride: %4==0 (b128 align), d-offset 4 banks (2-way max = free)
#define NBL   (NB * LTOT)

// fast transcendentals: v_exp/v_log/v_rcp based; rel err ~1e-7, budget 2.7e-4
__device__ __forceinline__ float siluf(float x){
  return x * __builtin_amdgcn_rcpf(1.f + __expf(-x));
}
__device__ __forceinline__ float softplusf(float x){
  return fmaxf(x, 0.f) + __logf(1.f + __expf(-fabsf(x)));
}

// 16-lane (row-aligned) sum via DPP butterflies — pure VALU, no DS ops.
__device__ __forceinline__ float red16(float x){
  int v;
  v = __float_as_int(x);
  x += __int_as_float(__builtin_amdgcn_update_dpp(0, v, 0xB1, 0xF, 0xF, true));   // quad_perm xor1
  v = __float_as_int(x);
  x += __int_as_float(__builtin_amdgcn_update_dpp(0, v, 0x4E, 0xF, 0xF, true));   // quad_perm xor2
  v = __float_as_int(x);
  x += __int_as_float(__builtin_amdgcn_update_dpp(0, v, 0x141, 0xF, 0xF, true));  // row_half_mirror
  v = __float_as_int(x);
  x += __int_as_float(__builtin_amdgcn_update_dpp(0, v, 0x140, 0xF, 0xF, true));  // row_mirror
  return x;
}

// floor(sqrt(v)) exact for 0 <= v <= 2^24 via rn + one-step fixup
__device__ __forceinline__ int isqrt_floor(int v){
  int r = __float2int_rn(sqrtf((float)v));
  if (r * r > v) --r;
  else if ((r + 1) * (r + 1) <= v) ++r;
  return r;
}

// perm k=0 (scanA): i = n*HW + r -> spatial n*HW + sp[r]
__device__ __forceinline__ int rho0(int i, const int* __restrict__ sp){
  int n = i >> 14; int r = i & (HWSZ - 1);
  return (n << 14) + sp[r];
}
// perm k=1 (scanB): i = r*6 + n ; tid = (r even ? n : 5-n) -> tid*HW + sp[r]
__device__ __forceinline__ int rho1(int i, const int* __restrict__ sp){
  unsigned ui = (unsigned)i;
  unsigned r = ui / 6u; unsigned n = ui - r * 6u;
  unsigned t = (r & 1u) ? (5u - n) : n;
  return (int)((t << 14) + (unsigned)sp[r]);
}

// ---------------- prep: analytic stable rank -> sp & spinv + input scatter ------------------
__global__ __launch_bounds__(128) void k_prep(const float* __restrict__ X,
                                              int* __restrict__ sp,
                                              int* __restrict__ spinv,
                                              float* __restrict__ xs0,
                                              float* __restrict__ xs1){
  const int j = blockIdx.x * 128 + threadIdx.x;   // 0..16383
  const int y = j >> 7, x = j & 127;
  const int dy = y - 64, dx = x - 64;
  const int v = dy*dy + dx*dx;
  // strictly-smaller-d2 count: clipped circle, rows dy' in [-64,63], cols dx' in [-64,63]
  int cnt = 0;
  for (int yy = 0; yy < 128; ++yy){
    int dyy = yy - 64;
    int w = v - dyy*dyy;                          // need dx'^2 < w
    if (w > 0){
      int m = isqrt_floor(w - 1);                 // largest |dx'| with dx'^2 < w
      int lo = m < 64 ? m : 64;
      int hi = m < 63 ? m : 63;
      cnt += lo + hi + 1;
    }
  }
  // same-bin (d2 == v), smaller flat index: rows above, plus same-row mirror
  {
    const int r = isqrt_floor(v);
    int yp0 = 64 - r; if (yp0 < 0) yp0 = 0;
    int yp1 = 64 + r + 1; if (yp1 > y) yp1 = y;
    for (int yp = yp0; yp < yp1; ++yp){
      int dyp = yp - 64;
      int tt = v - dyp*dyp;                       // >= 0 by construction
      int rr = isqrt_floor(tt);
      if (rr * rr == tt){
        cnt += (rr <= 64) ? 1 : 0;                // x = 64 - rr
        cnt += (rr >= 1 && rr <= 63) ? 1 : 0;     // x = 64 + rr, distinct
      }
    }
    if (x > 64) cnt += 1;                         // same-row mirror 128-x precedes
  }
  spinv[j] = cnt;
  sp[cnt]  = j;
  // scatter input into scan orders: xs0[b][m*HW+cnt] = X[b][m*HW+j];
  // xs1[b][cnt*6 + n] = X[b][m*HW+j], n = (cnt even)? m : 5-m
  #pragma unroll
  for (int b = 0; b < NB; ++b){
    const float* Xb = X + (size_t)b * LTOT;
    float* p0 = xs0 + (size_t)b * LTOT;
    float* p1 = xs1 + (size_t)b * LTOT;
    #pragma unroll
    for (int m = 0; m < 6; ++m){
      const float xv = Xb[m * HWSZ + j];
      p0[m * HWSZ + cnt] = xv;
      const int n1 = (cnt & 1) ? (5 - m) : m;
      p1[cnt * 6 + n1] = xv;
    }
  }
}

// ---------------- pass 1: per-chunk pipeline + from-zero scan; caches xm/zs -----------------
__global__ __launch_bounds__(128, 4)
void k_scan(const float* __restrict__ xs0, const float* __restrict__ xs1,
            const float* __restrict__ dww, const float* __restrict__ dwb,
            const float* __restrict__ ipw,
            const float* __restrict__ c1w, const float* __restrict__ c1b,
            const float* __restrict__ xpw,
            const float* __restrict__ dtpw, const float* __restrict__ dtpb,
            const float* __restrict__ Alog,
            float* __restrict__ chA, float* __restrict__ chB,
            float* __restrict__ y0g,
            float* __restrict__ xmg, float* __restrict__ zsg)
{
  const int c = blockIdx.x, b = blockIdx.y;
  const int c0 = c * TCH;
  const int tid = threadIdx.x;
  const size_t cb = (size_t)b * NCH + c;

  __shared__ __align__(16) float s_pre[(TCH + 3) * 9];
  __shared__ __align__(16) float s_dt[8 * SD];
  __shared__ __align__(16) float s_dxm[8 * SD];     // dt * xm (s-independent product)
  __shared__ __align__(16) float s_Bv[16 * SD];
  __shared__ __align__(16) float s_Cv[16 * SD];

  // ---- step A: contiguous loads from pre-permuted xs -> dwconv+silu -> in_proj; cache zs
  if (tid < TCH + 3){
    const int m = tid;
    const int i = c0 - 3 + m;
    if (i < 0){
      #pragma unroll
      for (int d = 0; d < 8; ++d) s_pre[m*9 + d] = 0.f;
    } else {
      const float* p0 = xs0 + (size_t)b * LTOT;
      const float* p1 = xs1 + (size_t)b * LTOT;
      const int iL = LTOT - 1 - i;
      const bool okm = (i > 0), okp = (i < LTOT - 1);
      float xv[12];
      xv[0]  = okm ? p0[i - 1]  : 0.f;
      xv[1]  =       p0[i];
      xv[2]  = okp ? p0[i + 1]  : 0.f;
      xv[3]  = okm ? p1[i - 1]  : 0.f;
      xv[4]  =       p1[i];
      xv[5]  = okp ? p1[i + 1]  : 0.f;
      xv[6]  = okm ? p0[iL + 1] : 0.f;
      xv[7]  =       p0[iL];
      xv[8]  = okp ? p0[iL - 1] : 0.f;
      xv[9]  = okm ? p1[iL + 1] : 0.f;
      xv[10] =       p1[iL];
      xv[11] = okp ? p1[iL - 1] : 0.f;
      float u[4];
      #pragma unroll
      for (int k = 0; k < 4; ++k){
        float acc = dwb[k];
        acc = fmaf(dww[k*3+0], xv[k*3+0], acc);
        acc = fmaf(dww[k*3+1], xv[k*3+1], acc);
        acc = fmaf(dww[k*3+2], xv[k*3+2], acc);
        u[k] = siluf(acc);
      }
      #pragma unroll
      for (int d = 0; d < 8; ++d){
        float acc =      ipw[d*4+0] * u[0];
        acc = fmaf(ipw[d*4+1], u[1], acc);
        acc = fmaf(ipw[d*4+2], u[2], acc);
        acc = fmaf(ipw[d*4+3], u[3], acc);
        s_pre[m*9 + d] = acc;
      }
      if (m >= 3){                                  // z gate -> global cache
        const int t0 = m - 3;
        float zs8[8];
        #pragma unroll
        for (int d = 0; d < 8; ++d){
          float acc =      ipw[(8+d)*4+0] * u[0];
          acc = fmaf(ipw[(8+d)*4+1], u[1], acc);
          acc = fmaf(ipw[(8+d)*4+2], u[2], acc);
          acc = fmaf(ipw[(8+d)*4+3], u[3], acc);
          zs8[d] = siluf(acc);
        }
        float* pz = zsg + (cb*96 + t0)*8;
        *reinterpret_cast<float4*>(pz)     = make_float4(zs8[0], zs8[1], zs8[2], zs8[3]);
        *reinterpret_cast<float4*>(pz + 4) = make_float4(zs8[4], zs8[5], zs8[6], zs8[7]);
      }
    }
  }
  __syncthreads();

  // ---- step B: conv4+silu -> xm (cached) ; x_proj -> dt, B, C (C stays in LDS)
  if (tid < TCH){
    const int t = tid;
    float xm[8];
    #pragma unroll
    for (int d = 0; d < 8; ++d){
      float acc = c1b[d];
      #pragma unroll
      for (int tau = 0; tau < 4; ++tau)
        acc = fmaf(c1w[d*4+tau], s_pre[(t+tau)*9 + d], acc);
      xm[d] = siluf(acc);
    }
    {
      float* px = xmg + (cb*96 + t)*8;
      *reinterpret_cast<float4*>(px)     = make_float4(xm[0], xm[1], xm[2], xm[3]);
      *reinterpret_cast<float4*>(px + 4) = make_float4(xm[4], xm[5], xm[6], xm[7]);
    }
    float dtr = xpw[0] * xm[0];
    #pragma unroll
    for (int d = 1; d < 8; ++d) dtr = fmaf(xpw[d], xm[d], dtr);
    #pragma unroll
    for (int s = 0; s < 16; ++s){
      float acc = xpw[(1+s)*8] * xm[0];
      #pragma unroll
      for (int d = 1; d < 8; ++d) acc = fmaf(xpw[(1+s)*8+d], xm[d], acc);
      s_Bv[s*SD + t] = acc;
      float acc2 = xpw[(17+s)*8] * xm[0];
      #pragma unroll
      for (int d = 1; d < 8; ++d) acc2 = fmaf(xpw[(17+s)*8+d], xm[d], acc2);
      s_Cv[s*SD + t] = acc2;
    }
    #pragma unroll
    for (int d = 0; d < 8; ++d){
      float dtv = softplusf(fmaf(dtpw[d], dtr, dtpb[d]));
      s_dt[d*SD + t]  = dtv;
      s_dxm[d*SD + t] = dtv * xm[d];
    }
  }
  __syncthreads();

  // ---- step C: from-zero scan; emit y0 (s==0 lanes), chunk summary
  {
    const int d = tid >> 4, s = tid & 15;
    const float Ads = -__expf(Alog[tid]);   // tid == d*16+s
    float h = 0.f, sdt = 0.f;
    const float* pdt = s_dt + d*SD;
    const float* pdx = s_dxm + d*SD;
    const float* pB  = s_Bv + s*SD;
    const float* pC  = s_Cv + s*SD;
    float* yb = y0g + cb * 768 + d * 96;
    for (int t0 = 0; t0 < TCH; t0 += 4){
      const float4 dt4 = *reinterpret_cast<const float4*>(pdt + t0);
      const float4 dx4 = *reinterpret_cast<const float4*>(pdx + t0);
      const float4 B4  = *reinterpret_cast<const float4*>(pB + t0);
      const float4 C4  = *reinterpret_cast<const float4*>(pC + t0);
      sdt += dt4.x + dt4.y + dt4.z + dt4.w;
      float y0, y1, y2, y3;
      { float dA = __expf(dt4.x*Ads); h = fmaf(dA, h, dx4.x*B4.x); y0 = h*C4.x; }
      { float dA = __expf(dt4.y*Ads); h = fmaf(dA, h, dx4.y*B4.y); y1 = h*C4.y; }
      { float dA = __expf(dt4.z*Ads); h = fmaf(dA, h, dx4.z*B4.z); y2 = h*C4.z; }
      { float dA = __expf(dt4.w*Ads); h = fmaf(dA, h, dx4.w*B4.w); y3 = h*C4.w; }
      y0 = red16(y0); y1 = red16(y1); y2 = red16(y2); y3 = red16(y3);
      if (s == 0)
        *reinterpret_cast<float4*>(yb + t0) = make_float4(y0, y1, y2, y3);
    }
    const size_t base = cb * 128 + tid;
    chA[base] = __expf(Ads * sdt);          // product of dA over the chunk
    chB[base] = h;
  }
}

// ---------------- combine: wave-parallel scan over chunks -> full h_in per chunk ------------
__global__ __launch_bounds__(128) void k_comb(const float* __restrict__ chA,
                                              const float* __restrict__ chB,
                                              float* __restrict__ hin){
  const int wave = (blockIdx.x << 1) | (threadIdx.x >> 6);  // 0..511 chain id
  const int lane = threadIdx.x & 63;
  const int b   = wave >> 7;
  const int idx = wave & 127;
  const size_t basebi = (size_t)b * NCH * 128 + idx;
  float carry = 0.f;
  float a = chA[basebi + (size_t)lane * 128];
  float h = chB[basebi + (size_t)lane * 128];
  for (int seg = 0; seg < NCH / 64; ++seg){
    float aN = 1.f, hN = 0.f;
    if (seg + 1 < NCH / 64){
      const size_t off = basebi + (size_t)((seg + 1) * 64 + lane) * 128;
      aN = chA[off]; hN = chB[off];
    }
    #pragma unroll
    for (int o = 1; o < 64; o <<= 1){
      float aj = __shfl_up(a, o, 64);
      float hj = __shfl_up(h, o, 64);
      if (lane >= o){ h = fmaf(a, hj, h); a *= aj; }
    }
    float ae = __shfl_up(a, 1, 64);
    float he = __shfl_up(h, 1, 64);
    if (lane == 0){ ae = 1.f; he = 0.f; }
    hin[basebi + (size_t)(seg * 64 + lane) * 128] = fmaf(ae, carry, he);
    float aL = __shfl(a, 63, 64);
    float hL = __shfl(h, 63, 64);
    carry = fmaf(aL, carry, hL);
    a = aN; h = hN;
  }
}

// ---------------- pass 2: correction + epilogue -> SoA planes (coalesced stores) ------------
__global__ __launch_bounds__(128)
void k_corr(const float* __restrict__ xmg, const float* __restrict__ zsg,
            const float* __restrict__ y0g, const float* __restrict__ hin,
            const float* __restrict__ xpw,
            const float* __restrict__ dtpw, const float* __restrict__ dtpb,
            const float* __restrict__ Alog, const float* __restrict__ Dp,
            const float* __restrict__ opw,
            const float* __restrict__ lng, const float* __restrict__ lnb,
            float* __restrict__ outbuf)   // SoA: [e][b][i]
{
  const int c = blockIdx.x, b = blockIdx.y;
  const int c0 = c * TCH;
  const int tid = threadIdx.x;
  const size_t cb = (size_t)b * NCH + c;

  __shared__ float s_hA[256];                   // [0:128) hin, [128:256) Ads
  __shared__ __align__(16) float s_sg[8 * 104]; // dt then in-place cumsum -> sigma
  __shared__ __align__(16) float s_Ct[96 * 20]; // C transposed [t][s], stride 20
  __shared__ float s_yf[8 * 96];

  // stage 0: constants
  s_hA[tid]       = hin[cb * 128 + tid];
  s_hA[128 + tid] = -__expf(Alog[tid]);

  // stage 1: from cached xm: rebuild C row + dt (bit-identical op order to k_scan)
  if (tid < TCH){
    const float* px = xmg + (cb*96 + tid)*8;
    const float4 xa = *reinterpret_cast<const float4*>(px);
    const float4 xb = *reinterpret_cast<const float4*>(px + 4);
    const float xm8[8] = {xa.x, xa.y, xa.z, xa.w, xb.x, xb.y, xb.z, xb.w};
    float dtr = xpw[0] * xm8[0];
    #pragma unroll
    for (int d = 1; d < 8; ++d) dtr = fmaf(xpw[d], xm8[d], dtr);
    float* pct = s_Ct + tid*20;
    #pragma unroll
    for (int s = 0; s < 16; ++s){
      float acc = xpw[(17+s)*8] * xm8[0];
      #pragma unroll
      for (int d = 1; d < 8; ++d) acc = fmaf(xpw[(17+s)*8+d], xm8[d], acc);
      pct[s] = acc;
    }
    #pragma unroll
    for (int d = 0; d < 8; ++d)
      s_sg[d*104 + tid] = softplusf(fmaf(dtpw[d], dtr, dtpb[d]));
  }
  __syncthreads();

  // stage 2: in-place inclusive cumsum of dt -> sigma (8 serial lanes, same order as k_scan)
  if (tid < 8){
    float* ps = s_sg + tid*104;
    float run = 0.f;
    for (int t0 = 0; t0 < TCH; t0 += 4){
      const float4 d4 = *reinterpret_cast<const float4*>(ps + t0);
      float r0 = run + d4.x, r1 = r0 + d4.y, r2 = r1 + d4.z, r3 = r2 + d4.w;
      *reinterpret_cast<float4*>(ps + t0) = make_float4(r0, r1, r2, r3);
      run = r3;
    }
  }
  __syncthreads();

  // stage 3: correction, lanes = (d, tsub), in-register s-accumulation
  {
    const int d = tid >> 4, tsub = tid & 15;
    float w[16], A16[16];
    #pragma unroll
    for (int s = 0; s < 16; ++s){
      w[s]   = s_hA[d*16 + s];
      A16[s] = s_hA[128 + d*16 + s];
    }
    const float* py0 = y0g + cb * 768 + d * 96;
    #pragma unroll
    for (int t = tsub; t < TCH; t += 16){
      const float sg = s_sg[d*104 + t];
      float acc = py0[t];
      const float* pc = s_Ct + t*20;
      #pragma unroll
      for (int s4 = 0; s4 < 16; s4 += 4){
        const float4 C4 = *reinterpret_cast<const float4*>(pc + s4);
        acc = fmaf(C4.x, __expf(A16[s4+0]*sg) * w[s4+0], acc);
        acc = fmaf(C4.y, __expf(A16[s4+1]*sg) * w[s4+1], acc);
        acc = fmaf(C4.z, __expf(A16[s4+2]*sg) * w[s4+2], acc);
        acc = fmaf(C4.w, __expf(A16[s4+3]*sg) * w[s4+3], acc);
      }
      s_yf[d*96 + t] = acc;
    }
  }
  __syncthreads();

  // stage 4: epilogue (skip+gate+out_proj+LN) -> SoA planes, coalesced
  if (tid < TCH){
    const int t = tid;
    const int i = c0 + t;
    const float* px = xmg + (cb*96 + t)*8;
    const float* pz = zsg + (cb*96 + t)*8;
    const float4 xa = *reinterpret_cast<const float4*>(px);
    const float4 xb = *reinterpret_cast<const float4*>(px + 4);
    const float4 za = *reinterpret_cast<const float4*>(pz);
    const float4 zb = *reinterpret_cast<const float4*>(pz + 4);
    const float xm8[8] = {xa.x, xa.y, xa.z, xa.w, xb.x, xb.y, xb.z, xb.w};
    const float zs8[8] = {za.x, za.y, za.z, za.w, zb.x, zb.y, zb.z, zb.w};
    float y[8];
    #pragma unroll
    for (int d = 0; d < 8; ++d)
      y[d] = (s_yf[d*96 + t] + xm8[d] * Dp[d]) * zs8[d];
    float o[4];
    #pragma unroll
    for (int e = 0; e < 4; ++e){
      float acc = opw[e*8] * y[0];
      #pragma unroll
      for (int d = 1; d < 8; ++d) acc = fmaf(opw[e*8+d], y[d], acc);
      o[e] = acc;
    }
    const float mu = 0.25f * (o[0] + o[1] + o[2] + o[3]);
    const float v0 = o[0] - mu, v1 = o[1] - mu, v2 = o[2] - mu, v3 = o[3] - mu;
    const float inv = rsqrtf(0.25f * (v0*v0 + v1*v1 + v2*v2 + v3*v3) + 1e-5f);
    const size_t base = (size_t)b * LTOT + i;
    outbuf[0*NBL + base] = fmaf(v0 * inv, lng[0], lnb[0]);
    outbuf[1*NBL + base] = fmaf(v1 * inv, lng[1], lnb[1]);
    outbuf[2*NBL + base] = fmaf(v2 * inv, lng[2], lnb[2]);
    outbuf[3*NBL + base] = fmaf(v3 * inv, lng[3], lnb[3]);
  }
}

// ---------------- final gather + mean (SoA planes) ----------------
__global__ __launch_bounds__(256) void k_final(const float* __restrict__ outbuf,
                                               const int* __restrict__ sp,
                                               float* __restrict__ out){
  const int l = blockIdx.x * 256 + threadIdx.x;   // spatial flat index 0..L-1
  const int b = blockIdx.y;
  const int q0 = rho0(l, sp), q1 = rho1(l, sp);
  const int j  = LTOT - 1 - l;
  const int q2 = rho0(j, sp), q3 = rho1(j, sp);
  const size_t pb = (size_t)b * LTOT;
  out[pb + l] = 0.25f * (outbuf[0*NBL + pb + q0] + outbuf[1*NBL + pb + q1] +
                         outbuf[2*NBL + pb + q2] + outbuf[3*NBL + pb + q3]);
}

extern "C" void kernel_launch(void* const* d_in, const int* in_sizes, int n_in,
                              void* d_out, int out_size, void* d_ws, size_t ws_size,
                              hipStream_t stream) {
  const float* X    = (const float*)d_in[0];   // (4,6,128,128)
  const float* dww  = (const float*)d_in[1];   // (4,1,3)
  const float* dwb  = (const float*)d_in[2];   // (4)
  const float* ipw  = (const float*)d_in[3];   // (16,4)
  const float* c1w  = (const float*)d_in[4];   // (8,1,4)
  const float* c1b  = (const float*)d_in[5];   // (8)
  const float* xpw  = (const float*)d_in[6];   // (33,8)
  const float* dtpw = (const float*)d_in[7];   // (8,1)
  const float* dtpb = (const float*)d_in[8];   // (8)
  const float* Alog = (const float*)d_in[9];   // (8,16)
  const float* Dp   = (const float*)d_in[10];  // (8)
  const float* opw  = (const float*)d_in[11];  // (4,8)
  const float* lng  = (const float*)d_in[12];  // (4)
  const float* lnb  = (const float*)d_in[13];  // (4)
  float* out = (float*)d_out;

  // workspace layout (all rewritten every call), ~54 MB:
  //   sp/spinv 2 x 16384 int | xs0/xs1 2 x 393216 f32 | chA/chB/hin 3 x 524288 f32
  //   y0g 3145728 | xmg/zsg 2 x 3145728 | outbuf 1572864   (f32)
  int* wsI     = (int*)d_ws;
  int* sp      = wsI;
  int* spinv   = wsI + 16384;
  float* xs0   = (float*)(wsI + 32768);
  float* xs1   = xs0 + NBL;
  float* chA   = xs1 + NBL;
  float* chB   = chA + 524288;
  float* hin   = chB + 524288;
  float* y0g   = hin + 524288;
  float* xmg   = y0g + 3145728;
  float* zsg   = xmg + 3145728;
  float* outbuf = zsg + 3145728;

  k_prep<<<128, 128, 0, stream>>>(X, sp, spinv, xs0, xs1);
  k_scan<<<dim3(NCH, NB), 128, 0, stream>>>(xs0, xs1, dww, dwb, ipw, c1w, c1b, xpw,
      dtpw, dtpb, Alog, chA, chB, y0g, xmg, zsg);
  k_comb<<<256, 128, 0, stream>>>(chA, chB, hin);
  k_corr<<<dim3(NCH, NB), 128, 0, stream>>>(xmg, zsg, y0g, hin,
      xpw, dtpw, dtpb, Alog, Dp, opw, lng, lnb, outbuf);
  k_final<<<dim3(LTOT / 256, NB), 256, 0, stream>>>(outbuf, sp, out);
}